// Round 9
// baseline (1890.870 us; speedup 1.0000x reference)
//
#include <hip/hip_runtime.h>

typedef __attribute__((ext_vector_type(8))) short bf16x8;
typedef __attribute__((ext_vector_type(4))) float f32x4;

// B=64, T=512, D=256, H=512, L=4, 4H=2048
// 32 wgs per layer (16 hcols each), 256 threads (4 waves) per wg. Grid 128.
// Round-5 LLC protocol (proven). v9: polls moved to iteration END (validate
// next step's inputs), loop top runs ONE merged pipelined GEMM -> single
// LLC lead-in per step instead of poll+leadin+poll+leadin.
#define WPL 32
#define NT 256
#define RING 8

__device__ __forceinline__ unsigned short f2bf(float f) {
  unsigned int u = __float_as_uint(f);
  u += 0x7FFFu + ((u >> 16) & 1u);
  return (unsigned short)(u >> 16);
}
__device__ __forceinline__ float sigmoid_fast(float x) {
  return __builtin_amdgcn_rcpf(1.0f + __builtin_amdgcn_exp2f(-1.4426950408889634f * x));
}
__device__ __forceinline__ float tanh_fast(float x) {
  return 1.0f - 2.0f * __builtin_amdgcn_rcpf(
                           1.0f + __builtin_amdgcn_exp2f(2.885390081777927f * x));
}
__device__ __forceinline__ void wait_vm0() {
  asm volatile("s_waitcnt vmcnt(0)" ::: "memory");
  __builtin_amdgcn_sched_barrier(0);
}
#define WAITVM(N)                                         \
  do {                                                    \
    asm volatile("s_waitcnt vmcnt(" #N ")" ::: "memory"); \
    __builtin_amdgcn_sched_barrier(0);                    \
  } while (0)

// MODE: 0 = plain cached (read-only x), 2 = sc0 sc1 (LLC coherent h)
template <int MODE>
__device__ __forceinline__ void ldA(bf16x8& d, int voff, const unsigned short* base) {
  if constexpr (MODE == 0)
    asm volatile("global_load_dwordx4 %0, %1, %2"
                 : "=v"(d) : "v"(voff), "s"(base));
  else
    asm volatile("global_load_dwordx4 %0, %1, %2 sc0 sc1"
                 : "=v"(d) : "v"(voff), "s"(base));
}
__device__ __forceinline__ unsigned ld_flag(const unsigned* p) {
  unsigned v;
  asm volatile("global_load_dword %0, %1, off sc0 sc1\n\ts_waitcnt vmcnt(0)"
               : "=v"(v) : "v"(p) : "memory");
  return v;
}
__device__ __forceinline__ void st16_coh(void* p, f32x4 v) {
  asm volatile("global_store_dwordx4 %0, %1, off sc0 sc1" :: "v"(p), "v"(v) : "memory");
}
__device__ __forceinline__ void st4_coh(void* p, unsigned v) {
  asm volatile("global_store_dword %0, %1, off sc0 sc1" :: "v"(p), "v"(v) : "memory");
}

// ---------------- prep kernels ----------------

// x [B,T,D] f32 -> xfrag [T][c(8)][bt(4)][lane(64)][e(8)] bf16, lane-linear
__global__ void cvt_x_kernel(const float* __restrict__ x,
                             unsigned short* __restrict__ xf) {
  int tid = blockIdx.x * 256 + threadIdx.x;  // 1,048,576
  int t     = tid >> 11;
  int inner = tid & 2047;
  int lane  = inner & 63;
  int bt    = (inner >> 6) & 3;
  int c     = inner >> 8;
  int b = bt * 16 + (lane & 15);
  int d = c * 32 + (lane >> 4) * 8;
  const float* s = x + ((size_t)b * 512 + t) * 256 + d;
  f32x4 v0 = *(const f32x4*)s;
  f32x4 v1 = *(const f32x4*)(s + 4);
  bf16x8 o;
  o[0] = (short)f2bf(v0[0]); o[1] = (short)f2bf(v0[1]);
  o[2] = (short)f2bf(v0[2]); o[3] = (short)f2bf(v0[3]);
  o[4] = (short)f2bf(v1[0]); o[5] = (short)f2bf(v1[1]);
  o[6] = (short)f2bf(v1[2]); o[7] = (short)f2bf(v1[3]);
  *(bf16x8*)(xf + (size_t)t * 16384 + (size_t)inner * 8) = o;
}

// W/U f32 -> wfrag [w(32)][g(4)][c(C2)][lane(64)][e(8)] bf16
__global__ void cvt_w_kernel(const float* __restrict__ W,
                             const float* __restrict__ U,
                             unsigned short* __restrict__ dst,
                             int C2, int split) {
  int tid = blockIdx.x * 256 + threadIdx.x;
  int lane = tid & 63;
  int c    = (tid >> 6) % C2;
  int rest = tid / (64 * C2);
  int g = rest & 3;
  int w = rest >> 2;
  int row = g * 512 + w * 16 + (lane & 15);
  int k   = c * 32 + (lane >> 4) * 8;
  const float* s = (k < split) ? (W + (size_t)row * split + k)
                               : (U + (size_t)row * 512 + (k - split));
  f32x4 v0 = *(const f32x4*)s;
  f32x4 v1 = *(const f32x4*)(s + 4);
  bf16x8 o;
  o[0] = (short)f2bf(v0[0]); o[1] = (short)f2bf(v0[1]);
  o[2] = (short)f2bf(v0[2]); o[3] = (short)f2bf(v0[3]);
  o[4] = (short)f2bf(v1[0]); o[5] = (short)f2bf(v1[1]);
  o[6] = (short)f2bf(v1[2]); o[7] = (short)f2bf(v1[3]);
  *(bf16x8*)(dst + (size_t)tid * 8) = o;
}

__global__ void bias_kernel(const float* __restrict__ bw,
                            const float* __restrict__ bu,
                            float* __restrict__ dst) {
  int i = blockIdx.x * 256 + threadIdx.x;  // 2048
  dst[i] = bw[i] + bu[i];
}

__global__ void zero_flags(unsigned int* __restrict__ p) {
  int i = blockIdx.x * 256 + threadIdx.x;  // 2048
  p[i] = 0u;
}

// ---------------- pipelined merged GEMM (C2 chunks over two bases) ----------------
// A from global frag layout; B from LDS frag layout. 3-phase-deep A pipeline,
// counted vmcnt (4 loads/phase); double-buffered B. Requires vmcnt==0 at
// entry; leaves vmcnt==0 at exit.
template <int C1, int C2, int M1, int M2>
__device__ __forceinline__ void gemm_run(const unsigned short* __restrict__ a1,
                                         const unsigned short* __restrict__ a2,
                                         const char* bg0, const char* bg1,
                                         const char* bg2, const char* bg3,
                                         int voffA, f32x4 acc[4]) {
  constexpr int NP = C2 / 4;
  bf16x8 av[3][4];
  bf16x8 bb[2][4][4];
  const char* bgp[4] = {bg0, bg1, bg2, bg3};

  auto issueA_iter = [&](int cc, int s3, int i) {
    if (cc < C1)
      ldA<M1>(av[s3][i], voffA + cc * 4096, a1);
    else
      ldA<M2>(av[s3][i], voffA + (cc - C1) * 4096, a2);
  };
  auto issueA_phase = [&](int q) {
#pragma unroll
    for (int i = 0; i < 4; ++i) issueA_iter(4 * q + i, q % 3, i);
  };
  auto loadB_phase = [&](int q) {
#pragma unroll
    for (int i = 0; i < 4; ++i)
#pragma unroll
      for (int g = 0; g < 4; ++g)
        bb[q & 1][i][g] = *(const bf16x8*)(bgp[g] + (4 * q + i) * 1024);
  };

#pragma unroll
  for (int q = 0; q < 3; ++q)
    if (q < NP) issueA_phase(q);
  loadB_phase(0);

#pragma unroll
  for (int ph = 0; ph < NP; ++ph) {
    if (ph + 1 < NP) loadB_phase(ph + 1);
    if (ph < NP - 2) {
      WAITVM(8);
    } else if (ph == NP - 2) {
      WAITVM(4);
    } else {
      WAITVM(0);
    }
#pragma unroll
    for (int i = 0; i < 4; ++i)
#pragma unroll
      for (int g = 0; g < 4; ++g)
        acc[g] = __builtin_amdgcn_mfma_f32_16x16x32_bf16(av[ph % 3][i],
                                                         bb[ph & 1][i][g],
                                                         acc[g], 0, 0, 0);
    if (ph + 3 < NP) issueA_phase(ph + 3);
  }
}

// ---------------- main persistent kernel ----------------
// grid 128: layer = bid>>5, w = bid&31 (hcols w*16..+16).
// 4 waves: wave vm owns m-tile rows vm*16..+16, full K.
__global__ void __launch_bounds__(NT, 1)
lstm_main(const unsigned short* __restrict__ xfrag,
          const unsigned short* __restrict__ wf0,
          const unsigned short* __restrict__ wf1,
          const unsigned short* __restrict__ wf2,
          const unsigned short* __restrict__ wf3,
          const float* __restrict__ bias,
          unsigned short* __restrict__ hbuf,
          unsigned int* __restrict__ flags,
          float* __restrict__ out) {
  extern __shared__ char smem[];

  const int bid   = blockIdx.x;
  const int layer = bid >> 5;
  const int w     = bid & 31;
  const int tid   = threadIdx.x;
  const int lane  = tid & 63;
  const int vm    = tid >> 6;
  const int l15   = lane & 15;
  const int lhi   = lane >> 4;
  const int hcol  = w * 16 + l15;
  const int C2r   = (layer == 0) ? 24 : 32;
  const int HOFF  = 4 * C2r * 64 * 16;  // LDS h-transpose buffer offset

  const unsigned short* wfl =
      (layer == 0) ? wf0 : (layer == 1) ? wf1 : (layer == 2) ? wf2 : wf3;
  const unsigned short* wsl = wfl + (size_t)w * (4 * C2r * 64 * 8);

  // stage weights into LDS (frag-linear; one-time)
  for (int i = tid; i < 4 * C2r * 64; i += NT)
    *(f32x4*)(smem + (size_t)i * 16) = *(const f32x4*)(wsl + (size_t)i * 8);
  __syncthreads();

  const char* bg[4];
#pragma unroll
  for (int g = 0; g < 4; ++g) bg[g] = smem + ((size_t)g * C2r * 64 + lane) * 16;

  float bv[4];
#pragma unroll
  for (int g = 0; g < 4; ++g) bv[g] = bias[layer * 2048 + g * 512 + hcol];

  float creg[4];
#pragma unroll
  for (int r = 0; r < 4; ++r) creg[r] = 0.f;

  const int voffA = lane * 16 + vm * 1024;
  const int base_w = (w >> 1) * 2048 + (w & 1) * 256;  // shorts

  const unsigned short* hprev =
      (layer == 0) ? nullptr : (hbuf + (size_t)(layer - 1) * RING * 32768);
  const unsigned short* hself = hbuf + (size_t)layer * RING * 32768;

  // h publish store thread mapping (tid < 128)
  const int sb_bt = tid >> 5;
  const int sb_q  = (tid >> 4) & 1;
  const int sb_bl = tid & 15;
  const int slot_off = base_w + sb_bt * 512 + sb_q * 128 + sb_bl * 8;

  // ---- prologue poll: validate t=0 cross input (h_prev(0)) ----
  if (layer > 0 && vm == 0) {
    const unsigned* fp = flags;
    unsigned need = 0;
    if (lane < 32) {
      fp = flags + ((layer - 1) * 32 + lane) * 16;
      need = 1u;
    }
    while (true) {
      unsigned v = need ? ld_flag(fp) : 0u;
      if (__ballot(need && v < need) == 0) break;
      __builtin_amdgcn_s_sleep(1);
    }
  }
  __syncthreads();
  wait_vm0();  // staging/bias/poll drained: vmcnt==0 for the counted ladder

  for (int t = 0; t < 512; ++t) {
    // ---- merged pipelined GEMM (inputs validated by prior polls) ----
    const unsigned short* aW =
        (layer == 0) ? (xfrag + (size_t)t * 16384)
                     : (hprev + (size_t)(t & (RING - 1)) * 32768);
    const unsigned short* aU =
        hself + (size_t)((t - 1) & (RING - 1)) * 32768;

    f32x4 acc[4];
    const f32x4 z4 = {0.f, 0.f, 0.f, 0.f};
#pragma unroll
    for (int g = 0; g < 4; ++g) acc[g] = z4;

    if (t == 0) {
      if (layer == 0)
        gemm_run<8, 8, 0, 0>(aW, aW, bg[0], bg[1], bg[2], bg[3], voffA, acc);
      else
        gemm_run<16, 16, 2, 2>(aW, aW, bg[0], bg[1], bg[2], bg[3], voffA, acc);
    } else {
      if (layer == 0)
        gemm_run<8, 24, 0, 2>(aW, aU, bg[0], bg[1], bg[2], bg[3], voffA, acc);
      else
        gemm_run<16, 32, 2, 2>(aW, aU, bg[0], bg[1], bg[2], bg[3], voffA, acc);
    }

    // ---- gates + state; h -> LDS transpose ----
    float hreg[4], cnreg[4];
#pragma unroll
    for (int r = 0; r < 4; ++r) {
      float fg = sigmoid_fast(acc[0][r] + bv[0]);
      float ig = sigmoid_fast(acc[1][r] + bv[1]);
      float og = sigmoid_fast(acc[2][r] + bv[2]);
      float gg = tanh_fast(acc[3][r] + bv[3]);
      float cn = fg * creg[r] + ig * gg;
      creg[r] = cn;
      cnreg[r] = cn;
      float h = og * tanh_fast(cn);
      hreg[r] = h;
      *(unsigned short*)(smem + HOFF + (vm * 16 + lhi * 4 + r) * 32 + l15 * 2) =
          f2bf(h);
    }
    __syncthreads();

    // ---- coalesced coherent h publish (threads 0..127) ----
    if (tid < 128) {
      f32x4 hv = *(const f32x4*)(smem + HOFF + (sb_bt * 16 + sb_bl) * 32 + sb_q * 16);
      unsigned short* dst = hbuf +
          ((size_t)layer * RING + (t & (RING - 1))) * 32768 + slot_off;
      st16_coh(dst, hv);
      wait_vm0();
    }
    __syncthreads();
    if (tid == 0)
      st4_coh(flags + (layer * 32 + w) * 16, (unsigned)(t + 1));

    // ---- output stores (overlap the end-polls below) ----
    if (layer == 3) {
#pragma unroll
      for (int r = 0; r < 4; ++r) {
        int bidx = vm * 16 + lhi * 4 + r;
        out[(size_t)bidx * 262144 + (size_t)t * 512 + hcol] = hreg[r];
      }
    }
    if (t == 511) {
#pragma unroll
      for (int r = 0; r < 4; ++r) {
        int bidx = vm * 16 + lhi * 4 + r;
        out[16777216 + ((size_t)layer * 64 + bidx) * 512 + hcol] = hreg[r];
        out[16777216 + 131072 + ((size_t)layer * 64 + bidx) * 512 + hcol] = cnreg[r];
      }
    }

    // ---- end polls: validate iteration t+1's inputs ----
    // wave0 lanes 0-31: cross flag >= t+2 (h_prev(t+1) published+drained)
    // wave0 lanes 32-63: self flags >= t+1 (peers' h(t) published+drained)
    // wave1 lanes 0-31: ring credit (consumer consumed slot (t+1)&7's old data)
    if (t < 511) {
      if (vm == 0) {
        const unsigned* fp = flags;
        unsigned need = 0;
        if (lane < 32) {
          if (layer > 0) {
            fp = flags + ((layer - 1) * 32 + lane) * 16;
            need = (unsigned)(t + 2);
          }
        } else {
          fp = flags + (layer * 32 + (lane - 32)) * 16;
          need = (unsigned)(t + 1);
        }
        while (true) {
          unsigned v = need ? ld_flag(fp) : 0u;
          if (__ballot(need && v < need) == 0) break;
          __builtin_amdgcn_s_sleep(1);
        }
      } else if (vm == 1) {
        const unsigned* fp = flags;
        unsigned need = 0;
        if (lane < 32 && layer < 3 && (t + 1) >= RING) {
          fp = flags + ((layer + 1) * 32 + lane) * 16;
          need = (unsigned)(t + 2 - RING);
        }
        while (true) {
          unsigned v = need ? ld_flag(fp) : 0u;
          if (__ballot(need && v < need) == 0) break;
          __builtin_amdgcn_s_sleep(1);
        }
      }
      __syncthreads();
      wait_vm0();  // out[] stores + poll loads drained: ladder exact at loop top
    }
  }
}

extern "C" void kernel_launch(void* const* d_in, const int* in_sizes, int n_in,
                              void* d_out, int out_size, void* d_ws, size_t ws_size,
                              hipStream_t stream) {
  const float* x = (const float*)d_in[0];
  const float *W[4], *U[4], *bw[4], *bu[4];
  for (int l = 0; l < 4; ++l) {
    W[l]  = (const float*)d_in[1 + 4 * l];
    U[l]  = (const float*)d_in[2 + 4 * l];
    bw[l] = (const float*)d_in[3 + 4 * l];
    bu[l] = (const float*)d_in[4 + 4 * l];
  }

  char* ws = (char*)d_ws;
  unsigned short* xfrag = (unsigned short*)(ws + 0);        // 16,777,216
  unsigned short* wfr0  = (unsigned short*)(ws + 16777216); //  3,145,728
  unsigned short* wfr1  = (unsigned short*)(ws + 19922944); //  4,194,304
  unsigned short* wfr2  = (unsigned short*)(ws + 24117248); //  4,194,304
  unsigned short* wfr3  = (unsigned short*)(ws + 28311552); //  4,194,304
  float*          biasp = (float*)(ws + 32505856);          //     32,768
  unsigned short* hbuf  = (unsigned short*)(ws + 32538624); //  2,097,152
  unsigned int*   flags = (unsigned int*)(ws + 34635776);   //      8,192
  float* out = (float*)d_out;

  cvt_x_kernel<<<4096, 256, 0, stream>>>(x, xfrag);
  cvt_w_kernel<<<768, 256, 0, stream>>>(W[0], U[0], wfr0, 24, 256);
  cvt_w_kernel<<<1024, 256, 0, stream>>>(W[1], U[1], wfr1, 32, 512);
  cvt_w_kernel<<<1024, 256, 0, stream>>>(W[2], U[2], wfr2, 32, 512);
  cvt_w_kernel<<<1024, 256, 0, stream>>>(W[3], U[3], wfr3, 32, 512);
  bias_kernel<<<8, 256, 0, stream>>>(bw[0], bu[0], biasp + 0 * 2048);
  bias_kernel<<<8, 256, 0, stream>>>(bw[1], bu[1], biasp + 1 * 2048);
  bias_kernel<<<8, 256, 0, stream>>>(bw[2], bu[2], biasp + 2 * 2048);
  bias_kernel<<<8, 256, 0, stream>>>(bw[3], bu[3], biasp + 3 * 2048);
  zero_flags<<<8, 256, 0, stream>>>(flags);

  hipFuncSetAttribute((const void*)lstm_main,
                      hipFuncAttributeMaxDynamicSharedMemorySize, 135168);
  lstm_main<<<dim3(4 * WPL), dim3(NT), 135168, stream>>>(
      xfrag, wfr0, wfr1, wfr2, wfr3, biasp, hbuf, flags, out);
}